// Round 1
// baseline (2942.574 us; speedup 1.0000x reference)
//
#include <hip/hip_runtime.h>
#include <math.h>

#define N_NODES 50000
#define N_EDGES 600000
#define FATOM   78
#define DIM     128
#define HEADS   8
#define EDIM    12
#define LAYERS  4
#define NBATCH  512
#define NDFF    512
#define ASCALE  0.25f   // 1/sqrt(16)

__device__ __forceinline__ float wave_sum(float v){
  #pragma unroll
  for (int m=1;m<64;m<<=1) v += __shfl_xor(v, m);
  return v;
}

// ---------------- CSR build ----------------
__global__ void count_kernel(const int* __restrict__ ei, int* __restrict__ cnt){
  int e = blockIdx.x*256 + threadIdx.x;
  if (e < N_EDGES) atomicAdd(&cnt[ei[N_EDGES + e]], 1);
}

__global__ __launch_bounds__(1024) void scan_kernel(const int* __restrict__ cnt, int* __restrict__ row_start){
  __shared__ int lds[1024];
  __shared__ int carry;
  int tid = threadIdx.x;
  if (tid==0) carry = 0;
  __syncthreads();
  for (int base=0; base<N_NODES; base+=1024){
    int v = (base+tid < N_NODES) ? cnt[base+tid] : 0;
    lds[tid] = v;
    __syncthreads();
    for (int off=1; off<1024; off<<=1){
      int add = (tid>=off) ? lds[tid-off] : 0;
      __syncthreads();
      lds[tid] += add;
      __syncthreads();
    }
    int incl = lds[tid];
    int c = carry;
    if (base+tid < N_NODES) row_start[base+tid+1] = c + incl;
    __syncthreads();
    if (tid==1023) carry = c + incl;
    __syncthreads();
  }
  if (tid==0) row_start[0] = 0;
}

__global__ void scatter_kernel(const int* __restrict__ ei, int* __restrict__ cnt2,
                               const int* __restrict__ row_start, int* __restrict__ sorted_eid){
  int e = blockIdx.x*256 + threadIdx.x;
  if (e < N_EDGES){
    int d = ei[N_EDGES + e];
    int pos = atomicAdd(&cnt2[d], 1);
    sorted_eid[row_start[d] + pos] = e;
  }
}

// ---------------- generic fp32 GEMM: C[N,M] = A[N,K] @ W[K,M] + bias, opt relu ----------------
__global__ __launch_bounds__(256) void gemm_bias(
    const float* __restrict__ A, const float* __restrict__ W,
    const float* __restrict__ bias, float* __restrict__ C,
    int N, int K, int M, int relu)
{
  __shared__ float As[16][68];
  __shared__ float Bs[16][68];
  int tid = threadIdx.x;
  int bm = blockIdx.x * 64;
  int bn = blockIdx.y * 64;
  int tx = tid & 15, ty = tid >> 4;
  float acc[4][4] = {};
  for (int k0=0; k0<K; k0+=16){
    // A tile 64x16
    {
      int r  = tid >> 2;
      int kk = (tid & 3) << 2;
      int gr = bm + r, kg = k0 + kk;
      float a0=0.f,a1=0.f,a2=0.f,a3=0.f;
      if (gr < N){
        const float* Ap = A + (size_t)gr*K + kg;
        if (((K & 3)==0) && (kg+3 < K)){
          float4 t4 = *(const float4*)Ap; a0=t4.x; a1=t4.y; a2=t4.z; a3=t4.w;
        } else {
          if (kg   < K) a0 = Ap[0];
          if (kg+1 < K) a1 = Ap[1];
          if (kg+2 < K) a2 = Ap[2];
          if (kg+3 < K) a3 = Ap[3];
        }
      }
      As[kk+0][r]=a0; As[kk+1][r]=a1; As[kk+2][r]=a2; As[kk+3][r]=a3;
    }
    // W tile 16x64
    {
      int rb = tid >> 4;
      int cb = (tid & 15) << 2;
      int kg = k0 + rb;
      float4 b4 = {0.f,0.f,0.f,0.f};
      if (kg < K) b4 = *(const float4*)(W + (size_t)kg*M + bn + cb);
      Bs[rb][cb+0]=b4.x; Bs[rb][cb+1]=b4.y; Bs[rb][cb+2]=b4.z; Bs[rb][cb+3]=b4.w;
    }
    __syncthreads();
    #pragma unroll
    for (int kk=0; kk<16; ++kk){
      float av[4], bv[4];
      #pragma unroll
      for (int i=0;i<4;i++) av[i] = As[kk][ty*4+i];
      #pragma unroll
      for (int j=0;j<4;j++) bv[j] = Bs[kk][tx*4+j];
      #pragma unroll
      for (int i=0;i<4;i++)
        #pragma unroll
        for (int j=0;j<4;j++) acc[i][j] += av[i]*bv[j];
    }
    __syncthreads();
  }
  #pragma unroll
  for (int i=0;i<4;i++){
    int row = bm + ty*4 + i;
    if (row < N){
      #pragma unroll
      for (int j=0;j<4;j++){
        int col = bn + tx*4 + j;
        float val = acc[i][j] + bias[col];
        if (relu) val = fmaxf(val, 0.f);
        C[(size_t)row*M + col] = val;
      }
    }
  }
}

// ---------------- fused edge attention (per-dst-node wave, no atomics) ----------------
__global__ __launch_bounds__(256) void edge_attn_kernel(
  const float* __restrict__ q, const float* __restrict__ k, const float* __restrict__ v,
  const float* __restrict__ ea, const float* __restrict__ Wel, const float* __restrict__ bel,
  const int* __restrict__ ei, const int* __restrict__ row_start, const int* __restrict__ sorted_eid,
  float* __restrict__ exbuf, float* __restrict__ agg)
{
  int wid  = (blockIdx.x*blockDim.x + threadIdx.x) >> 6;
  int lane = threadIdx.x & 63;
  if (wid >= N_NODES) return;
  int ch = lane*2;
  float w0[12], w1[12];
  #pragma unroll
  for (int j=0;j<12;j++){ float2 t = *(const float2*)(Wel + j*DIM + ch); w0[j]=t.x; w1[j]=t.y; }
  float2 be2 = *(const float2*)(bel + ch);
  float2 q2  = *(const float2*)(q + (size_t)wid*DIM + ch);
  int rs = row_start[wid], re = row_start[wid+1];
  float den = 0.f;
  for (int i=rs; i<re; ++i){
    int eid = sorted_eid[i];
    int s   = ei[eid];                       // src node
    float eav = (lane < EDIM) ? ea[(size_t)eid*EDIM + lane] : 0.f;
    float e0 = be2.x, e1 = be2.y;
    #pragma unroll
    for (int j=0;j<12;j++){ float a = __shfl(eav, j); e0 += a*w0[j]; e1 += a*w1[j]; }
    float2 k2 = *(const float2*)(k + (size_t)s*DIM + ch);
    float p = q2.x*(k2.x+e0) + q2.y*(k2.y+e1);
    p += __shfl_xor(p,1); p += __shfl_xor(p,2); p += __shfl_xor(p,4);
    float ev = __expf(p * ASCALE);
    den += ev;
    if ((lane & 7) == 0) exbuf[(size_t)i*HEADS + (lane>>3)] = ev;
  }
  float inv = 1.f/(den + 1e-16f);
  float ax = 0.f, ay = 0.f;
  for (int i=rs; i<re; ++i){
    int eid = sorted_eid[i];
    int s   = ei[eid];
    float aval = exbuf[(size_t)i*HEADS + (lane>>3)] * inv;
    float eav = (lane < EDIM) ? ea[(size_t)eid*EDIM + lane] : 0.f;
    float e0 = be2.x, e1 = be2.y;
    #pragma unroll
    for (int j=0;j<12;j++){ float a = __shfl(eav, j); e0 += a*w0[j]; e1 += a*w1[j]; }
    float2 v2 = *(const float2*)(v + (size_t)s*DIM + ch);
    ax += (v2.x + e0)*aval;
    ay += (v2.y + e1)*aval;
  }
  float2 o; o.x = ax; o.y = ay;
  *(float2*)(agg + (size_t)wid*DIM + ch) = o;
}

// ---------------- beta gate + residual + LN1 (in-place h) ----------------
__global__ __launch_bounds__(256) void beta_ln_kernel(
  const float* __restrict__ agg, const float* __restrict__ xr, float* __restrict__ h,
  const float* __restrict__ Wb, const float* __restrict__ g, const float* __restrict__ b)
{
  int wid  = (blockIdx.x*blockDim.x + threadIdx.x) >> 6;
  int lane = threadIdx.x & 63;
  if (wid >= N_NODES) return;
  int ch = lane*2;
  float2 a2 = *(const float2*)(agg + (size_t)wid*DIM + ch);
  float2 x2 = *(const float2*)(xr  + (size_t)wid*DIM + ch);
  float2 h2 = *(const float2*)(h   + (size_t)wid*DIM + ch);
  float2 wa = *(const float2*)(Wb + ch);
  float2 wx = *(const float2*)(Wb + DIM + ch);
  float2 wd = *(const float2*)(Wb + 2*DIM + ch);
  float s = a2.x*wa.x + a2.y*wa.y + x2.x*wx.x + x2.y*wx.y
          + (a2.x-x2.x)*wd.x + (a2.y-x2.y)*wd.y;
  s = wave_sum(s);
  float beta = 1.f/(1.f + __expf(-s));
  float tx = beta*x2.x + (1.f-beta)*a2.x + h2.x;
  float ty = beta*x2.y + (1.f-beta)*a2.y + h2.y;
  float mu = wave_sum(tx+ty)*(1.f/128.f);
  float dx = tx-mu, dy = ty-mu;
  float var = wave_sum(dx*dx+dy*dy)*(1.f/128.f);
  float r = rsqrtf(var + 1e-5f);
  float2 gv = *(const float2*)(g+ch), bv = *(const float2*)(b+ch);
  float2 o; o.x = dx*r*gv.x + bv.x; o.y = dy*r*gv.y + bv.y;
  *(float2*)(h + (size_t)wid*DIM + ch) = o;
}

// ---------------- residual + LN2 (in-place h) ----------------
__global__ __launch_bounds__(256) void add_ln_kernel(
  const float* __restrict__ t_in, float* __restrict__ h,
  const float* __restrict__ g, const float* __restrict__ b)
{
  int wid  = (blockIdx.x*blockDim.x + threadIdx.x) >> 6;
  int lane = threadIdx.x & 63;
  if (wid >= N_NODES) return;
  int ch = lane*2;
  float2 t2 = *(const float2*)(t_in + (size_t)wid*DIM + ch);
  float2 h2 = *(const float2*)(h    + (size_t)wid*DIM + ch);
  float tx = t2.x + h2.x, ty = t2.y + h2.y;
  float mu = wave_sum(tx+ty)*(1.f/128.f);
  float dx = tx-mu, dy = ty-mu;
  float var = wave_sum(dx*dx+dy*dy)*(1.f/128.f);
  float r = rsqrtf(var + 1e-5f);
  float2 gv = *(const float2*)(g+ch), bv = *(const float2*)(b+ch);
  float2 o; o.x = dx*r*gv.x + bv.x; o.y = dy*r*gv.y + bv.y;
  *(float2*)(h + (size_t)wid*DIM + ch) = o;
}

// ---------------- mean pool (atomics) + output projection ----------------
__global__ __launch_bounds__(256) void pool_kernel(
  const float* __restrict__ h, const int* __restrict__ batch,
  float* __restrict__ pooled, float* __restrict__ cntB)
{
  int wid  = (blockIdx.x*blockDim.x + threadIdx.x) >> 6;
  int lane = threadIdx.x & 63;
  if (wid >= N_NODES) return;
  int b = batch[wid];
  int ch = lane*2;
  float2 h2 = *(const float2*)(h + (size_t)wid*DIM + ch);
  atomicAdd(&pooled[b*DIM + ch],     h2.x);
  atomicAdd(&pooled[b*DIM + ch + 1], h2.y);
  if (lane == 0) atomicAdd(&cntB[b], 1.0f);
}

__global__ __launch_bounds__(128) void out_kernel(
  const float* __restrict__ pooled, const float* __restrict__ cntB,
  const float* __restrict__ Wout, const float* __restrict__ bout,
  float* __restrict__ out)
{
  int b = blockIdx.x;
  int d = threadIdx.x;
  __shared__ float p[DIM];
  float invc = 1.f / fmaxf(cntB[b], 1.f);
  p[d] = pooled[b*DIM + d] * invc;
  __syncthreads();
  float s = bout[d];
  #pragma unroll 8
  for (int kk=0; kk<DIM; ++kk) s += p[kk]*Wout[kk*DIM + d];
  out[b*DIM + d] = s;
}

extern "C" void kernel_launch(void* const* d_in, const int* in_sizes, int n_in,
                              void* d_out, int out_size, void* d_ws, size_t ws_size,
                              hipStream_t stream)
{
  const float* x     = (const float*)d_in[0];
  const float* ea    = (const float*)d_in[1];
  const int*   ei    = (const int*)d_in[2];
  const int*   batch = (const int*)d_in[3];
  const float* Wemb  = (const float*)d_in[4];
  const float* bemb  = (const float*)d_in[5];
  const float* Wout  = (const float*)d_in[6];
  const float* bout  = (const float*)d_in[7];
  const float* Wq    = (const float*)d_in[8];
  const float* bq    = (const float*)d_in[9];
  const float* Wk    = (const float*)d_in[10];
  const float* bk    = (const float*)d_in[11];
  const float* Wv    = (const float*)d_in[12];
  const float* bv    = (const float*)d_in[13];
  const float* We    = (const float*)d_in[14];
  const float* be    = (const float*)d_in[15];
  const float* Wskip = (const float*)d_in[16];
  const float* bskip = (const float*)d_in[17];
  const float* Wbeta = (const float*)d_in[18];
  const float* g1    = (const float*)d_in[19];
  const float* b1    = (const float*)d_in[20];
  const float* g2    = (const float*)d_in[21];
  const float* b2    = (const float*)d_in[22];
  const float* Wf1   = (const float*)d_in[23];
  const float* bf1   = (const float*)d_in[24];
  const float* Wf2   = (const float*)d_in[25];
  const float* bf2   = (const float*)d_in[26];
  float* out = (float*)d_out;

  // workspace layout
  float* ws     = (float*)d_ws;
  float* h      = ws;                                   // N*128
  float* region = h + (size_t)N_NODES*DIM;              // N*512 (q|k|v|xr, reused as ff1)
  float* qb     = region;
  float* kb     = region + (size_t)N_NODES*DIM;
  float* vb     = region + (size_t)2*N_NODES*DIM;
  float* xrb    = region + (size_t)3*N_NODES*DIM;
  float* agg    = region + (size_t)N_NODES*NDFF;        // N*128 (also ff2 out)
  float* exbuf  = agg + (size_t)N_NODES*DIM;            // E*8
  float* pooled = exbuf + (size_t)N_EDGES*HEADS;        // B*128
  float* cntB   = pooled + NBATCH*DIM;                  // B
  int*   cnt        = (int*)(cntB + NBATCH);            // N
  int*   cnt2       = cnt + N_NODES;                    // N
  int*   row_start  = cnt2 + N_NODES;                   // N+1
  int*   sorted_eid = row_start + N_NODES + 1;          // E

  hipMemsetAsync(cnt,  0, N_NODES*sizeof(int), stream);
  hipMemsetAsync(cnt2, 0, N_NODES*sizeof(int), stream);
  hipMemsetAsync(pooled, 0, (NBATCH*DIM + NBATCH)*sizeof(float), stream);

  // CSR by destination node (reused across layers)
  count_kernel<<<(N_EDGES+255)/256, 256, 0, stream>>>(ei, cnt);
  scan_kernel<<<1, 1024, 0, stream>>>(cnt, row_start);
  scatter_kernel<<<(N_EDGES+255)/256, 256, 0, stream>>>(ei, cnt2, row_start, sorted_eid);

  dim3 blk(256);
  int gRows = (N_NODES + 63)/64;
  int nodeBlocks = (N_NODES + 3)/4;   // 4 waves per 256-block, 1 wave per node

  // h = x @ Wemb + bemb
  gemm_bias<<<dim3(gRows, DIM/64), blk, 0, stream>>>(x, Wemb, bemb, h, N_NODES, FATOM, DIM, 0);

  for (int l=0; l<LAYERS; ++l){
    const float* Wq_l = Wq + (size_t)l*DIM*DIM;
    const float* Wk_l = Wk + (size_t)l*DIM*DIM;
    const float* Wv_l = Wv + (size_t)l*DIM*DIM;
    const float* Ws_l = Wskip + (size_t)l*DIM*DIM;
    gemm_bias<<<dim3(gRows, DIM/64), blk, 0, stream>>>(h, Wq_l, bq+l*DIM, qb,  N_NODES, DIM, DIM, 0);
    gemm_bias<<<dim3(gRows, DIM/64), blk, 0, stream>>>(h, Wk_l, bk+l*DIM, kb,  N_NODES, DIM, DIM, 0);
    gemm_bias<<<dim3(gRows, DIM/64), blk, 0, stream>>>(h, Wv_l, bv+l*DIM, vb,  N_NODES, DIM, DIM, 0);
    gemm_bias<<<dim3(gRows, DIM/64), blk, 0, stream>>>(h, Ws_l, bskip+l*DIM, xrb, N_NODES, DIM, DIM, 0);

    edge_attn_kernel<<<nodeBlocks, 256, 0, stream>>>(
        qb, kb, vb, ea, We + (size_t)l*EDIM*DIM, be + l*DIM,
        ei, row_start, sorted_eid, exbuf, agg);

    beta_ln_kernel<<<nodeBlocks, 256, 0, stream>>>(
        agg, xrb, h, Wbeta + l*3*DIM, g1 + l*DIM, b1 + l*DIM);

    gemm_bias<<<dim3(gRows, NDFF/64), blk, 0, stream>>>(
        h, Wf1 + (size_t)l*DIM*NDFF, bf1 + l*NDFF, region, N_NODES, DIM, NDFF, 1);
    gemm_bias<<<dim3(gRows, DIM/64), blk, 0, stream>>>(
        region, Wf2 + (size_t)l*NDFF*DIM, bf2 + l*DIM, agg, N_NODES, NDFF, DIM, 0);

    add_ln_kernel<<<nodeBlocks, 256, 0, stream>>>(agg, h, g2 + l*DIM, b2 + l*DIM);
  }

  pool_kernel<<<nodeBlocks, 256, 0, stream>>>(h, batch, pooled, cntB);
  out_kernel<<<NBATCH, 128, 0, stream>>>(pooled, cntB, Wout, bout, out);
}

// Round 2
// 1291.103 us; speedup vs baseline: 2.2791x; 2.2791x over previous
//
#include <hip/hip_runtime.h>
#include <math.h>

#define N_NODES 50000
#define N_EDGES 600000
#define FATOM   78
#define DIM     128
#define HEADS   8
#define EDIM    12
#define LAYERS  4
#define NBATCH  512
#define NDFF    512
#define ASCALE  0.25f   // 1/sqrt(16)

typedef __attribute__((ext_vector_type(8))) short bf16x8;
typedef __attribute__((ext_vector_type(4))) float f32x4;

__device__ __forceinline__ float wave_sum(float v){
  #pragma unroll
  for (int m=1;m<64;m<<=1) v += __shfl_xor(v, m);
  return v;
}
__device__ __forceinline__ short f2b(float f){
  unsigned int u = __builtin_bit_cast(unsigned int, f);
  u += 0x7fffu + ((u>>16)&1u);
  return (short)(u>>16);
}
__device__ __forceinline__ float b2f_lo(unsigned int u){ return __builtin_bit_cast(float, u<<16); }
__device__ __forceinline__ float b2f_hi(unsigned int u){ return __builtin_bit_cast(float, u & 0xffff0000u); }

// ---------------- CSR build ----------------
__global__ void count_kernel(const int* __restrict__ ei, int* __restrict__ cnt){
  int e = blockIdx.x*256 + threadIdx.x;
  if (e < N_EDGES) atomicAdd(&cnt[ei[N_EDGES + e]], 1);
}

__global__ __launch_bounds__(1024) void scan_kernel(const int* __restrict__ cnt, int* __restrict__ row_start){
  __shared__ int lds[1024];
  __shared__ int carry;
  int tid = threadIdx.x;
  if (tid==0) carry = 0;
  __syncthreads();
  for (int base=0; base<N_NODES; base+=1024){
    int v = (base+tid < N_NODES) ? cnt[base+tid] : 0;
    lds[tid] = v;
    __syncthreads();
    for (int off=1; off<1024; off<<=1){
      int add = (tid>=off) ? lds[tid-off] : 0;
      __syncthreads();
      lds[tid] += add;
      __syncthreads();
    }
    int incl = lds[tid];
    int c = carry;
    if (base+tid < N_NODES) row_start[base+tid+1] = c + incl;
    __syncthreads();
    if (tid==1023) carry = c + incl;
    __syncthreads();
  }
  if (tid==0) row_start[0] = 0;
}

// scatter edges into dst-CSR order; also gather src id and edge_attr into sorted order
__global__ void scatter_kernel(const int* __restrict__ ei, const float* __restrict__ ea,
                               int* __restrict__ cnt2, const int* __restrict__ row_start,
                               int* __restrict__ src_s, float* __restrict__ ea_s){
  int e = blockIdx.x*256 + threadIdx.x;
  if (e < N_EDGES){
    int d = ei[N_EDGES + e];
    int pos = atomicAdd(&cnt2[d], 1);
    int p = row_start[d] + pos;
    src_s[p] = ei[e];
    #pragma unroll
    for (int j=0;j<EDIM;j++) ea_s[(size_t)p*EDIM + j] = ea[(size_t)e*EDIM + j];
  }
}

// ---------------- weight packing: transpose to [M][K] bf16 ----------------
__global__ __launch_bounds__(256) void pack_weights(
  const float* __restrict__ Wq, const float* __restrict__ Wk,
  const float* __restrict__ Wv, const float* __restrict__ Ws,
  const float* __restrict__ bq, const float* __restrict__ bk,
  const float* __restrict__ bv, const float* __restrict__ bs,
  const float* __restrict__ Wf1, const float* __restrict__ Wf2,
  short* __restrict__ wq_t, short* __restrict__ wf1_t, short* __restrict__ wf2_t,
  float* __restrict__ bqkvs)
{
  int l = blockIdx.y;
  int idx = blockIdx.x*256 + threadIdx.x;   // 0 .. 3*65536-1
  int sec = idx >> 16, r = idx & 65535;
  if (sec == 0){
    int n = r >> 7, k = r & 127;
    const float* W = (n<128)?Wq:(n<256)?Wk:(n<384)?Wv:Ws;
    float v = W[(size_t)l*16384 + k*128 + (n&127)];
    wq_t[(size_t)l*65536 + n*128 + k] = f2b(v);
    if (k == 0){
      const float* bb = (n<128)?bq:(n<256)?bk:(n<384)?bv:bs;
      bqkvs[l*512 + n] = bb[l*128 + (n&127)];
    }
  } else if (sec == 1){
    int n = r >> 7, k = r & 127;
    wf1_t[(size_t)l*65536 + n*128 + k] = f2b(Wf1[(size_t)l*65536 + k*512 + n]);
  } else {
    int n = r >> 9, k = r & 511;
    wf2_t[(size_t)l*65536 + n*512 + k] = f2b(Wf2[(size_t)l*65536 + k*128 + n]);
  }
}

__global__ void cast_h(const float* __restrict__ h, short* __restrict__ hb){
  int i = (blockIdx.x*256 + threadIdx.x)*2;
  unsigned int lo = (unsigned int)(unsigned short)f2b(h[i]);
  unsigned int hi = (unsigned int)(unsigned short)f2b(h[i+1]);
  *(unsigned int*)(hb + i) = lo | (hi<<16);
}

// ---------------- fp32 GEMM (embed only: K=78) ----------------
__global__ __launch_bounds__(256) void gemm_bias(
    const float* __restrict__ A, const float* __restrict__ W,
    const float* __restrict__ bias, float* __restrict__ C,
    int N, int K, int M)
{
  __shared__ float As[16][68];
  __shared__ float Bs[16][68];
  int tid = threadIdx.x;
  int bm = blockIdx.x * 64;
  int bn = blockIdx.y * 64;
  int tx = tid & 15, ty = tid >> 4;
  float acc[4][4] = {};
  for (int k0=0; k0<K; k0+=16){
    {
      int r  = tid >> 2;
      int kk = (tid & 3) << 2;
      int gr = bm + r, kg = k0 + kk;
      float a0=0.f,a1=0.f,a2=0.f,a3=0.f;
      if (gr < N){
        const float* Ap = A + (size_t)gr*K + kg;
        if (kg   < K) a0 = Ap[0];
        if (kg+1 < K) a1 = Ap[1];
        if (kg+2 < K) a2 = Ap[2];
        if (kg+3 < K) a3 = Ap[3];
      }
      As[kk+0][r]=a0; As[kk+1][r]=a1; As[kk+2][r]=a2; As[kk+3][r]=a3;
    }
    {
      int rb = tid >> 4;
      int cb = (tid & 15) << 2;
      int kg = k0 + rb;
      float4 b4 = {0.f,0.f,0.f,0.f};
      if (kg < K) b4 = *(const float4*)(W + (size_t)kg*M + bn + cb);
      Bs[rb][cb+0]=b4.x; Bs[rb][cb+1]=b4.y; Bs[rb][cb+2]=b4.z; Bs[rb][cb+3]=b4.w;
    }
    __syncthreads();
    #pragma unroll
    for (int kk=0; kk<16; ++kk){
      float av[4], bv[4];
      #pragma unroll
      for (int i=0;i<4;i++) av[i] = As[kk][ty*4+i];
      #pragma unroll
      for (int j=0;j<4;j++) bv[j] = Bs[kk][tx*4+j];
      #pragma unroll
      for (int i=0;i<4;i++)
        #pragma unroll
        for (int j=0;j<4;j++) acc[i][j] += av[i]*bv[j];
    }
    __syncthreads();
  }
  #pragma unroll
  for (int i=0;i<4;i++){
    int row = bm + ty*4 + i;
    if (row < N){
      #pragma unroll
      for (int j=0;j<4;j++){
        int col = bn + tx*4 + j;
        C[(size_t)row*M + col] = acc[i][j] + bias[col];
      }
    }
  }
}

// ---------------- bf16 MFMA GEMM: C[N,M] = A[N,K] @ Bt[M,K]^T + bias ----------------
// tile 128x128, BK=64, 4 waves (2x2), each wave 64x64 (4x4 frags of 16x16x32)
__global__ __launch_bounds__(256) void mfma_gemm(
    const short* __restrict__ A,   // bf16 [N][K]
    const short* __restrict__ Bt,  // bf16 [M][K]
    const float* __restrict__ bias,
    float* __restrict__ Cf,        // fp32 out (or null)
    short* __restrict__ Cb,        // bf16 out (or null)
    int Nrows, int K, int M, int relu)
{
  __shared__ short As[128*64];
  __shared__ short Bs[128*64];
  int tid  = threadIdx.x;
  int lane = tid & 63;
  int wave = tid >> 6;
  int wr = wave >> 1, wc = wave & 1;
  int bm = blockIdx.x * 128, bn = blockIdx.y * 128;

  f32x4 zero = {0.f,0.f,0.f,0.f};
  f32x4 acc[4][4];
  #pragma unroll
  for (int m=0;m<4;m++)
    #pragma unroll
    for (int n=0;n<4;n++) acc[m][n] = zero;

  int srow = tid >> 3;          // 0..31
  int soct = tid & 7;           // source 16B octet
  for (int k0 = 0; k0 < K; k0 += 64){
    #pragma unroll
    for (int it=0; it<4; ++it){
      int r = it*32 + srow;     // 0..127
      int gr = bm + r; if (gr >= Nrows) gr = Nrows-1;
      bf16x8 av = *(const bf16x8*)(A + (size_t)gr*K + k0 + soct*8);
      *(bf16x8*)(As + r*64 + ((soct ^ (r&7))<<3)) = av;
      bf16x8 bv = *(const bf16x8*)(Bt + (size_t)(bn + r)*K + k0 + soct*8);
      *(bf16x8*)(Bs + r*64 + ((soct ^ (r&7))<<3)) = bv;
    }
    __syncthreads();
    #pragma unroll
    for (int ks=0; ks<2; ++ks){
      bf16x8 af[4], bfv[4];
      #pragma unroll
      for (int m=0;m<4;m++){
        int row = wr*64 + m*16 + (lane&15);
        int oi  = ks*4 + (lane>>4);
        af[m] = *(const bf16x8*)(As + row*64 + ((oi ^ (row&7))<<3));
      }
      #pragma unroll
      for (int n=0;n<4;n++){
        int col = wc*64 + n*16 + (lane&15);
        int oi  = ks*4 + (lane>>4);
        bfv[n] = *(const bf16x8*)(Bs + col*64 + ((oi ^ (col&7))<<3));
      }
      #pragma unroll
      for (int m=0;m<4;m++)
        #pragma unroll
        for (int n=0;n<4;n++)
          acc[m][n] = __builtin_amdgcn_mfma_f32_16x16x32_bf16(af[m], bfv[n], acc[m][n], 0, 0, 0);
    }
    __syncthreads();
  }

  #pragma unroll
  for (int m=0;m<4;m++){
    #pragma unroll
    for (int n=0;n<4;n++){
      int col = bn + wc*64 + n*16 + (lane&15);
      float bval = bias[col];
      #pragma unroll
      for (int j=0;j<4;j++){
        int row = bm + wr*64 + m*16 + (lane>>4)*4 + j;
        if (row < Nrows){
          float v = acc[m][n][j] + bval;
          if (relu) v = fmaxf(v, 0.f);
          if (Cf) Cf[(size_t)row*M + col] = v;
          if (Cb) Cb[(size_t)row*M + col] = f2b(v);
        }
      }
    }
  }
}

// ---------------- fused edge attention + beta gate + LN1 (per-dst-node wave) ----------------
__global__ __launch_bounds__(256) void edge_attn_fused(
  const short* __restrict__ qkvx,     // bf16 [N][512]: q|k|v|xr
  const float* __restrict__ ea_s, const int* __restrict__ src_s,
  const float* __restrict__ Wel, const float* __restrict__ bel,
  const int* __restrict__ row_start,
  float* __restrict__ h, short* __restrict__ hb,
  const float* __restrict__ Wb, const float* __restrict__ g, const float* __restrict__ b)
{
  int wid  = (blockIdx.x*blockDim.x + threadIdx.x) >> 6;
  int lane = threadIdx.x & 63;
  if (wid >= N_NODES) return;
  int ch = lane*2;
  float w0[12], w1[12];
  #pragma unroll
  for (int j=0;j<12;j++){ float2 t = *(const float2*)(Wel + j*DIM + ch); w0[j]=t.x; w1[j]=t.y; }
  float2 be2 = *(const float2*)(bel + ch);
  unsigned int qw = *(const unsigned int*)(qkvx + (size_t)wid*512 + ch);
  float qx = b2f_lo(qw), qy = b2f_hi(qw);
  int rs = row_start[wid], re = row_start[wid+1];
  float den = 0.f, ax = 0.f, ay = 0.f;
  for (int i=rs; i<re; ++i){
    int s = src_s[i];
    float eav = (lane < EDIM) ? ea_s[(size_t)i*EDIM + lane] : 0.f;
    float e0 = be2.x, e1 = be2.y;
    #pragma unroll
    for (int j=0;j<12;j++){ float a = __shfl(eav, j); e0 += a*w0[j]; e1 += a*w1[j]; }
    unsigned int kw = *(const unsigned int*)(qkvx + (size_t)s*512 + 128 + ch);
    unsigned int vw = *(const unsigned int*)(qkvx + (size_t)s*512 + 256 + ch);
    float p = qx*(b2f_lo(kw)+e0) + qy*(b2f_hi(kw)+e1);
    p += __shfl_xor(p,1); p += __shfl_xor(p,2); p += __shfl_xor(p,4);
    float ev = __expf(p * ASCALE);
    den += ev;
    ax += ev*(b2f_lo(vw)+e0);
    ay += ev*(b2f_hi(vw)+e1);
  }
  float inv = 1.f/(den + 1e-16f);
  float agx = ax*inv, agy = ay*inv;
  // beta gate
  unsigned int xw = *(const unsigned int*)(qkvx + (size_t)wid*512 + 384 + ch);
  float xrx = b2f_lo(xw), xry = b2f_hi(xw);
  float2 h2 = *(const float2*)(h + (size_t)wid*DIM + ch);
  float2 wa = *(const float2*)(Wb + ch);
  float2 wx = *(const float2*)(Wb + DIM + ch);
  float2 wd = *(const float2*)(Wb + 2*DIM + ch);
  float s = agx*wa.x + agy*wa.y + xrx*wx.x + xry*wx.y
          + (agx-xrx)*wd.x + (agy-xry)*wd.y;
  s = wave_sum(s);
  float beta = 1.f/(1.f + __expf(-s));
  float tx = beta*xrx + (1.f-beta)*agx + h2.x;
  float ty = beta*xry + (1.f-beta)*agy + h2.y;
  float mu = wave_sum(tx+ty)*(1.f/128.f);
  float dx = tx-mu, dy = ty-mu;
  float var = wave_sum(dx*dx+dy*dy)*(1.f/128.f);
  float r = rsqrtf(var + 1e-5f);
  float2 gv = *(const float2*)(g+ch), bv = *(const float2*)(b+ch);
  float ox = dx*r*gv.x + bv.x, oy = dy*r*gv.y + bv.y;
  float2 o; o.x = ox; o.y = oy;
  *(float2*)(h + (size_t)wid*DIM + ch) = o;
  unsigned int lo = (unsigned int)(unsigned short)f2b(ox);
  unsigned int hi = (unsigned int)(unsigned short)f2b(oy);
  *(unsigned int*)(hb + (size_t)wid*DIM + ch) = lo | (hi<<16);
}

// ---------------- residual + LN2 (in-place h, also emits bf16) ----------------
__global__ __launch_bounds__(256) void add_ln_kernel(
  const float* __restrict__ t_in, float* __restrict__ h, short* __restrict__ hb,
  const float* __restrict__ g, const float* __restrict__ b)
{
  int wid  = (blockIdx.x*blockDim.x + threadIdx.x) >> 6;
  int lane = threadIdx.x & 63;
  if (wid >= N_NODES) return;
  int ch = lane*2;
  float2 t2 = *(const float2*)(t_in + (size_t)wid*DIM + ch);
  float2 h2 = *(const float2*)(h    + (size_t)wid*DIM + ch);
  float tx = t2.x + h2.x, ty = t2.y + h2.y;
  float mu = wave_sum(tx+ty)*(1.f/128.f);
  float dx = tx-mu, dy = ty-mu;
  float var = wave_sum(dx*dx+dy*dy)*(1.f/128.f);
  float r = rsqrtf(var + 1e-5f);
  float2 gv = *(const float2*)(g+ch), bv = *(const float2*)(b+ch);
  float ox = dx*r*gv.x + bv.x, oy = dy*r*gv.y + bv.y;
  float2 o; o.x = ox; o.y = oy;
  *(float2*)(h + (size_t)wid*DIM + ch) = o;
  unsigned int lo = (unsigned int)(unsigned short)f2b(ox);
  unsigned int hi = (unsigned int)(unsigned short)f2b(oy);
  *(unsigned int*)(hb + (size_t)wid*DIM + ch) = lo | (hi<<16);
}

// ---------------- mean pool (atomics) + output projection ----------------
__global__ __launch_bounds__(256) void pool_kernel(
  const float* __restrict__ h, const int* __restrict__ batch,
  float* __restrict__ pooled, float* __restrict__ cntB)
{
  int wid  = (blockIdx.x*blockDim.x + threadIdx.x) >> 6;
  int lane = threadIdx.x & 63;
  if (wid >= N_NODES) return;
  int bch = batch[wid];
  int ch = lane*2;
  float2 h2 = *(const float2*)(h + (size_t)wid*DIM + ch);
  atomicAdd(&pooled[bch*DIM + ch],     h2.x);
  atomicAdd(&pooled[bch*DIM + ch + 1], h2.y);
  if (lane == 0) atomicAdd(&cntB[bch], 1.0f);
}

__global__ __launch_bounds__(128) void out_kernel(
  const float* __restrict__ pooled, const float* __restrict__ cntB,
  const float* __restrict__ Wout, const float* __restrict__ bout,
  float* __restrict__ out)
{
  int bidx = blockIdx.x;
  int d = threadIdx.x;
  __shared__ float p[DIM];
  float invc = 1.f / fmaxf(cntB[bidx], 1.f);
  p[d] = pooled[bidx*DIM + d] * invc;
  __syncthreads();
  float s = bout[d];
  #pragma unroll 8
  for (int kk=0; kk<DIM; ++kk) s += p[kk]*Wout[kk*DIM + d];
  out[bidx*DIM + d] = s;
}

extern "C" void kernel_launch(void* const* d_in, const int* in_sizes, int n_in,
                              void* d_out, int out_size, void* d_ws, size_t ws_size,
                              hipStream_t stream)
{
  const float* x     = (const float*)d_in[0];
  const float* ea    = (const float*)d_in[1];
  const int*   ei    = (const int*)d_in[2];
  const int*   batch = (const int*)d_in[3];
  const float* Wemb  = (const float*)d_in[4];
  const float* bemb  = (const float*)d_in[5];
  const float* Wout  = (const float*)d_in[6];
  const float* bout  = (const float*)d_in[7];
  const float* Wq    = (const float*)d_in[8];
  const float* bq    = (const float*)d_in[9];
  const float* Wk    = (const float*)d_in[10];
  const float* bk    = (const float*)d_in[11];
  const float* Wv    = (const float*)d_in[12];
  const float* bv    = (const float*)d_in[13];
  const float* We    = (const float*)d_in[14];
  const float* be    = (const float*)d_in[15];
  const float* Wskip = (const float*)d_in[16];
  const float* bskip = (const float*)d_in[17];
  const float* Wbeta = (const float*)d_in[18];
  const float* g1    = (const float*)d_in[19];
  const float* b1    = (const float*)d_in[20];
  const float* g2    = (const float*)d_in[21];
  const float* b2    = (const float*)d_in[22];
  const float* Wf1   = (const float*)d_in[23];
  const float* bf1   = (const float*)d_in[24];
  const float* Wf2   = (const float*)d_in[25];
  const float* bf2   = (const float*)d_in[26];
  float* out = (float*)d_out;

  // ---- workspace layout ----
  float* ws     = (float*)d_ws;
  float* h      = ws;                       // N*128
  float* ffout  = h + (size_t)N_NODES*DIM;  // N*128
  float* ea_s   = ffout + (size_t)N_NODES*DIM;       // E*12
  float* pooled = ea_s + (size_t)N_EDGES*EDIM;       // B*128
  float* cntB   = pooled + NBATCH*DIM;               // B
  float* bqkvs  = cntB + NBATCH;                     // L*512
  short* hb     = (short*)(bqkvs + LAYERS*512);      // N*128
  short* region = hb + (size_t)N_NODES*DIM;          // N*512
  short* wq_t   = region + (size_t)N_NODES*NDFF;     // L*512*128
  short* wf1_t  = wq_t  + (size_t)LAYERS*NDFF*DIM;   // L*512*128
  short* wf2_t  = wf1_t + (size_t)LAYERS*NDFF*DIM;   // L*128*512
  int*   cnt       = (int*)(wf2_t + (size_t)LAYERS*NDFF*DIM);
  int*   cnt2      = cnt + N_NODES;
  int*   row_start = cnt2 + N_NODES;                 // N+1
  int*   src_s     = row_start + N_NODES + 1;        // E

  hipMemsetAsync(cnt,  0, N_NODES*sizeof(int), stream);
  hipMemsetAsync(cnt2, 0, N_NODES*sizeof(int), stream);
  hipMemsetAsync(pooled, 0, (NBATCH*DIM + NBATCH)*sizeof(float), stream);

  // CSR by destination + sorted src/edge_attr
  count_kernel<<<(N_EDGES+255)/256, 256, 0, stream>>>(ei, cnt);
  scan_kernel<<<1, 1024, 0, stream>>>(cnt, row_start);
  scatter_kernel<<<(N_EDGES+255)/256, 256, 0, stream>>>(ei, ea, cnt2, row_start, src_s, ea_s);

  // pack weights (bf16, transposed) + fused qkvs bias
  pack_weights<<<dim3(768, LAYERS), 256, 0, stream>>>(
      Wq, Wk, Wv, Wskip, bq, bk, bv, bskip, Wf1, Wf2, wq_t, wf1_t, wf2_t, bqkvs);

  // h = x @ Wemb + bemb (fp32), then cast to bf16
  gemm_bias<<<dim3((N_NODES+63)/64, DIM/64), 256, 0, stream>>>(x, Wemb, bemb, h, N_NODES, FATOM, DIM);
  cast_h<<<(N_NODES*DIM/2 + 255)/256, 256, 0, stream>>>(h, hb);

  int gM = (N_NODES + 127)/128;
  int nodeBlocks = (N_NODES + 3)/4;

  for (int l=0; l<LAYERS; ++l){
    // fused Q|K|V|skip projection -> region bf16 [N][512]
    mfma_gemm<<<dim3(gM, 4), 256, 0, stream>>>(
        hb, wq_t + (size_t)l*NDFF*DIM, bqkvs + l*512, nullptr, region,
        N_NODES, DIM, NDFF, 0);

    // attention + beta gate + LN1 -> h, hb
    edge_attn_fused<<<nodeBlocks, 256, 0, stream>>>(
        region, ea_s, src_s, We + (size_t)l*EDIM*DIM, be + l*DIM, row_start,
        h, hb, Wbeta + l*3*DIM, g1 + l*DIM, b1 + l*DIM);

    // FF1 (relu) -> region bf16 [N][512]
    mfma_gemm<<<dim3(gM, 4), 256, 0, stream>>>(
        hb, wf1_t + (size_t)l*NDFF*DIM, bf1 + l*NDFF, nullptr, region,
        N_NODES, DIM, NDFF, 1);

    // FF2 -> ffout fp32 [N][128]
    mfma_gemm<<<dim3(gM, 1), 256, 0, stream>>>(
        region, wf2_t + (size_t)l*DIM*NDFF, bf2 + l*DIM, ffout, nullptr,
        N_NODES, NDFF, DIM, 0);

    // residual + LN2 -> h, hb
    add_ln_kernel<<<nodeBlocks, 256, 0, stream>>>(ffout, h, hb, g2 + l*DIM, b2 + l*DIM);
  }

  pool_kernel<<<nodeBlocks, 256, 0, stream>>>(h, batch, pooled, cntB);
  out_kernel<<<NBATCH, 128, 0, stream>>>(pooled, cntB, Wout, bout, out);
}

// Round 3
// 1084.072 us; speedup vs baseline: 2.7144x; 1.1910x over previous
//
#include <hip/hip_runtime.h>
#include <math.h>

#define N_NODES 50000
#define N_EDGES 600000
#define FATOM   78
#define DIM     128
#define HEADS   8
#define EDIM    12
#define LAYERS  4
#define NBATCH  512
#define NDFF    512
#define ASCALE  0.25f   // 1/sqrt(16)

typedef __attribute__((ext_vector_type(8))) short bf16x8;
typedef __attribute__((ext_vector_type(4))) float f32x4;

__device__ __forceinline__ float half_sum(float v){
  #pragma unroll
  for (int m=1;m<32;m<<=1) v += __shfl_xor(v, m);
  return v;
}
__device__ __forceinline__ short f2b(float f){
  unsigned int u = __builtin_bit_cast(unsigned int, f);
  u += 0x7fffu + ((u>>16)&1u);
  return (short)(u>>16);
}
__device__ __forceinline__ float b2f_lo(unsigned int u){ return __builtin_bit_cast(float, u<<16); }
__device__ __forceinline__ float b2f_hi(unsigned int u){ return __builtin_bit_cast(float, u & 0xffff0000u); }

__device__ __forceinline__ void gload16(const short* g, short* l){
  __builtin_amdgcn_global_load_lds(
      (const __attribute__((address_space(1))) void*)g,
      (__attribute__((address_space(3))) void*)l, 16, 0, 0);
}

// ---------------- CSR build ----------------
__global__ void count_kernel(const int* __restrict__ ei, int* __restrict__ cnt){
  int e = blockIdx.x*256 + threadIdx.x;
  if (e < N_EDGES) atomicAdd(&cnt[ei[N_EDGES + e]], 1);
}

// two-level parallel scan
__global__ __launch_bounds__(1024) void scan1(const int* __restrict__ cnt,
                                              int* __restrict__ row_start, int* __restrict__ bsum){
  __shared__ int lds[1024];
  int gid = blockIdx.x*1024 + threadIdx.x;
  int v = (gid < N_NODES) ? cnt[gid] : 0;
  lds[threadIdx.x] = v; __syncthreads();
  for (int off=1; off<1024; off<<=1){
    int add = (threadIdx.x>=off)?lds[threadIdx.x-off]:0;
    __syncthreads();
    lds[threadIdx.x]+=add;
    __syncthreads();
  }
  if (gid < N_NODES) row_start[gid+1] = lds[threadIdx.x];
  if (threadIdx.x==1023) bsum[blockIdx.x] = lds[1023];
}
__global__ void scan2(int* __restrict__ bsum, int nb){
  int tid = threadIdx.x;
  int v = (tid < nb) ? bsum[tid] : 0;
  #pragma unroll
  for (int off=1; off<64; off<<=1){
    int u = __shfl_up(v, off);
    if (tid >= off) v += u;
  }
  if (tid < nb) bsum[tid] = v;   // inclusive
}
__global__ void scan3(int* __restrict__ row_start, const int* __restrict__ bsum){
  int gid = blockIdx.x*256 + threadIdx.x;
  if (gid == 0) row_start[0] = 0;
  if (gid < N_NODES){
    int blk = gid >> 10;
    if (blk > 0) row_start[gid+1] += bsum[blk-1];
  }
}

__global__ void scatter_kernel(const int* __restrict__ ei, const float* __restrict__ ea,
                               int* __restrict__ cnt2, const int* __restrict__ row_start,
                               int* __restrict__ src_s, float* __restrict__ ea_s){
  int e = blockIdx.x*256 + threadIdx.x;
  if (e < N_EDGES){
    int d = ei[N_EDGES + e];
    int pos = atomicAdd(&cnt2[d], 1);
    int p = row_start[d] + pos;
    src_s[p] = ei[e];
    #pragma unroll
    for (int j=0;j<EDIM;j++) ea_s[(size_t)p*EDIM + j] = ea[(size_t)e*EDIM + j];
  }
}

// ---------------- weight packing: transpose to [M][K] bf16 ----------------
__global__ __launch_bounds__(256) void pack_weights(
  const float* __restrict__ Wq, const float* __restrict__ Wk,
  const float* __restrict__ Wv, const float* __restrict__ Ws,
  const float* __restrict__ bq, const float* __restrict__ bk,
  const float* __restrict__ bv, const float* __restrict__ bs,
  const float* __restrict__ Wf1, const float* __restrict__ Wf2,
  short* __restrict__ wq_t, short* __restrict__ wf1_t, short* __restrict__ wf2_t,
  float* __restrict__ bqkvs)
{
  int l = blockIdx.y;
  int idx = blockIdx.x*256 + threadIdx.x;   // 0 .. 3*65536-1
  int sec = idx >> 16, r = idx & 65535;
  if (sec == 0){
    int n = r >> 7, k = r & 127;
    const float* W = (n<128)?Wq:(n<256)?Wk:(n<384)?Wv:Ws;
    float v = W[(size_t)l*16384 + k*128 + (n&127)];
    wq_t[(size_t)l*65536 + n*128 + k] = f2b(v);
    if (k == 0){
      const float* bb = (n<128)?bq:(n<256)?bk:(n<384)?bv:bs;
      bqkvs[l*512 + n] = bb[l*128 + (n&127)];
    }
  } else if (sec == 1){
    int n = r >> 7, k = r & 127;
    wf1_t[(size_t)l*65536 + n*128 + k] = f2b(Wf1[(size_t)l*65536 + k*512 + n]);
  } else {
    int n = r >> 9, k = r & 511;
    wf2_t[(size_t)l*65536 + n*512 + k] = f2b(Wf2[(size_t)l*65536 + k*128 + n]);
  }
}

__global__ void pack_emb(const float* __restrict__ Wemb, short* __restrict__ wemb_t){
  int idx = blockIdx.x*256 + threadIdx.x;     // 128*128
  int nn = idx >> 7, k = idx & 127;
  wemb_t[nn*128 + k] = (k < FATOM) ? f2b(Wemb[(size_t)k*DIM + nn]) : (short)0;
}

__global__ void cast_pad_x(const float* __restrict__ x, short* __restrict__ xb){
  int idx = blockIdx.x*256 + threadIdx.x;     // N*64 u32-pairs
  int n = idx >> 6, kp = (idx & 63)*2;
  if (n >= N_NODES) return;
  float v0 = (kp   < FATOM) ? x[(size_t)n*FATOM + kp]   : 0.f;
  float v1 = (kp+1 < FATOM) ? x[(size_t)n*FATOM + kp+1] : 0.f;
  unsigned int lo = (unsigned int)(unsigned short)f2b(v0);
  unsigned int hi = (unsigned int)(unsigned short)f2b(v1);
  *(unsigned int*)(xb + (size_t)n*128 + kp) = lo | (hi<<16);
}

// ---------------- bf16 MFMA GEMM: C[N,M] = A[N,K] @ Bt[M,K]^T + bias ----------------
// tile 128x128, BK=64, 4 waves (2x2); global_load_lds staging with
// source-side XOR swizzle (oct ^= row&7), linear LDS dest, swizzled ds_read.
__global__ __launch_bounds__(256) void mfma_gemm(
    const short* __restrict__ A,   // bf16 [N][K]
    const short* __restrict__ Bt,  // bf16 [M][K]
    const float* __restrict__ bias,
    float* __restrict__ Cf,        // fp32 out (or null)
    short* __restrict__ Cb,        // bf16 out (or null)
    int Nrows, int K, int M, int relu)
{
  __shared__ short As[128*64];
  __shared__ short Bs[128*64];
  int tid  = threadIdx.x;
  int lane = tid & 63;
  int wave = tid >> 6;
  int wr = wave >> 1, wc = wave & 1;
  int bm = blockIdx.x * 128, bn = blockIdx.y * 128;

  f32x4 zero = {0.f,0.f,0.f,0.f};
  f32x4 acc[4][4];
  #pragma unroll
  for (int m=0;m<4;m++)
    #pragma unroll
    for (int n=0;n<4;n++) acc[m][n] = zero;

  int r0 = wave*32;
  for (int k0 = 0; k0 < K; k0 += 64){
    #pragma unroll
    for (int it=0; it<4; ++it){
      int rr = r0 + it*8;
      int r  = rr + (lane>>3);
      int oct = (lane&7) ^ (r&7);
      int gr = bm + r; if (gr >= Nrows) gr = Nrows-1;
      gload16(A  + (size_t)gr*K       + k0 + oct*8, As + rr*64);
      gload16(Bt + (size_t)(bn + r)*K + k0 + oct*8, Bs + rr*64);
    }
    __syncthreads();
    #pragma unroll
    for (int ks=0; ks<2; ++ks){
      bf16x8 af[4], bfv[4];
      #pragma unroll
      for (int m=0;m<4;m++){
        int row = wr*64 + m*16 + (lane&15);
        int oi  = ks*4 + (lane>>4);
        af[m] = *(const bf16x8*)(As + row*64 + ((oi ^ (row&7))<<3));
      }
      #pragma unroll
      for (int n=0;n<4;n++){
        int col = wc*64 + n*16 + (lane&15);
        int oi  = ks*4 + (lane>>4);
        bfv[n] = *(const bf16x8*)(Bs + col*64 + ((oi ^ (col&7))<<3));
      }
      #pragma unroll
      for (int m=0;m<4;m++)
        #pragma unroll
        for (int n=0;n<4;n++)
          acc[m][n] = __builtin_amdgcn_mfma_f32_16x16x32_bf16(af[m], bfv[n], acc[m][n], 0, 0, 0);
    }
    __syncthreads();
  }

  #pragma unroll
  for (int m=0;m<4;m++){
    #pragma unroll
    for (int n=0;n<4;n++){
      int col = bn + wc*64 + n*16 + (lane&15);
      float bval = bias[col];
      #pragma unroll
      for (int j=0;j<4;j++){
        int row = bm + wr*64 + m*16 + (lane>>4)*4 + j;
        if (row < Nrows){
          float v = acc[m][n][j] + bval;
          if (relu) v = fmaxf(v, 0.f);
          if (Cf) Cf[(size_t)row*M + col] = v;
          if (Cb) Cb[(size_t)row*M + col] = f2b(v);
        }
      }
    }
  }
}

// ---------------- fused edge attention + beta gate + LN1 ----------------
// 32 lanes per dst node (2 nodes/wave = 2 independent memory streams), 4 ch/lane
__global__ __launch_bounds__(256) void edge_attn_fused(
  const short* __restrict__ qkvx,     // bf16 [N][512]: q|k|v|xr
  const float* __restrict__ ea_s, const int* __restrict__ src_s,
  const float* __restrict__ Wel, const float* __restrict__ bel,
  const int* __restrict__ row_start,
  float* __restrict__ h, short* __restrict__ hb,
  const float* __restrict__ Wb, const float* __restrict__ g, const float* __restrict__ b)
{
  int wid = (blockIdx.x*256 + threadIdx.x) >> 5;   // one node per 32 lanes
  if (wid >= N_NODES) return;
  int ln = threadIdx.x & 31;
  int c0 = ln*4;

  float4 w4[12];
  #pragma unroll
  for (int j=0;j<EDIM;j++) w4[j] = *(const float4*)(Wel + j*DIM + c0);
  float4 be4 = *(const float4*)(bel + c0);

  const short* qrow = qkvx + (size_t)wid*512;
  uint2 qu = *(const uint2*)(qrow + c0);
  float q0=b2f_lo(qu.x), q1=b2f_hi(qu.x), q2=b2f_lo(qu.y), q3=b2f_hi(qu.y);

  int rs = row_start[wid], re = row_start[wid+1];
  float den=0.f, a0=0.f, a1=0.f, a2=0.f, a3=0.f;
  for (int i=rs; i<re; ++i){
    int s = src_s[i];
    const float* eap = ea_s + (size_t)i*EDIM;
    float e0=be4.x, e1=be4.y, e2=be4.z, e3=be4.w;
    #pragma unroll
    for (int j=0;j<EDIM;j++){
      float a = eap[j];
      e0 += a*w4[j].x; e1 += a*w4[j].y; e2 += a*w4[j].z; e3 += a*w4[j].w;
    }
    const short* srow = qkvx + (size_t)s*512;
    uint2 ku = *(const uint2*)(srow + 128 + c0);
    uint2 vu = *(const uint2*)(srow + 256 + c0);
    float p = q0*(b2f_lo(ku.x)+e0) + q1*(b2f_hi(ku.x)+e1)
            + q2*(b2f_lo(ku.y)+e2) + q3*(b2f_hi(ku.y)+e3);
    p += __shfl_xor(p,1); p += __shfl_xor(p,2);   // 16-ch head reduce (4-lane group)
    float ev = __expf(p * ASCALE);
    den += ev;
    a0 += ev*(b2f_lo(vu.x)+e0); a1 += ev*(b2f_hi(vu.x)+e1);
    a2 += ev*(b2f_lo(vu.y)+e2); a3 += ev*(b2f_hi(vu.y)+e3);
  }
  float inv = 1.f/(den + 1e-16f);
  float g0=a0*inv, g1=a1*inv, g2=a2*inv, g3=a3*inv;

  // beta gate
  uint2 xu = *(const uint2*)(qrow + 384 + c0);
  float x0=b2f_lo(xu.x), x1=b2f_hi(xu.x), x2=b2f_lo(xu.y), x3=b2f_hi(xu.y);
  float4 hv = *(const float4*)(h + (size_t)wid*DIM + c0);
  float4 wa = *(const float4*)(Wb + c0);
  float4 wxv= *(const float4*)(Wb + DIM + c0);
  float4 wdv= *(const float4*)(Wb + 2*DIM + c0);
  float sacc = g0*wa.x + g1*wa.y + g2*wa.z + g3*wa.w
             + x0*wxv.x + x1*wxv.y + x2*wxv.z + x3*wxv.w
             + (g0-x0)*wdv.x + (g1-x1)*wdv.y + (g2-x2)*wdv.z + (g3-x3)*wdv.w;
  sacc = half_sum(sacc);
  float beta = 1.f/(1.f + __expf(-sacc));
  float t0 = beta*x0 + (1.f-beta)*g0 + hv.x;
  float t1 = beta*x1 + (1.f-beta)*g1 + hv.y;
  float t2 = beta*x2 + (1.f-beta)*g2 + hv.z;
  float t3 = beta*x3 + (1.f-beta)*g3 + hv.w;
  float mu = half_sum(t0+t1+t2+t3)*(1.f/128.f);
  float d0=t0-mu, d1=t1-mu, d2=t2-mu, d3=t3-mu;
  float var = half_sum(d0*d0+d1*d1+d2*d2+d3*d3)*(1.f/128.f);
  float r = rsqrtf(var + 1e-5f);
  float4 gv = *(const float4*)(g+c0);
  float4 bv = *(const float4*)(b+c0);
  float o0 = d0*r*gv.x+bv.x, o1 = d1*r*gv.y+bv.y, o2 = d2*r*gv.z+bv.z, o3 = d3*r*gv.w+bv.w;
  float4 o; o.x=o0; o.y=o1; o.z=o2; o.w=o3;
  *(float4*)(h + (size_t)wid*DIM + c0) = o;
  unsigned int u0 = (unsigned int)(unsigned short)f2b(o0) | ((unsigned int)(unsigned short)f2b(o1)<<16);
  unsigned int u1 = (unsigned int)(unsigned short)f2b(o2) | ((unsigned int)(unsigned short)f2b(o3)<<16);
  uint2 ou; ou.x=u0; ou.y=u1;
  *(uint2*)(hb + (size_t)wid*DIM + c0) = ou;
}

// ---------------- residual + LN2 (in-place h, also emits bf16) ----------------
__global__ __launch_bounds__(256) void add_ln_kernel(
  const float* __restrict__ t_in, float* __restrict__ h, short* __restrict__ hb,
  const float* __restrict__ g, const float* __restrict__ b)
{
  int wid = (blockIdx.x*256 + threadIdx.x) >> 5;
  if (wid >= N_NODES) return;
  int ln = threadIdx.x & 31;
  int c0 = ln*4;
  float4 t2 = *(const float4*)(t_in + (size_t)wid*DIM + c0);
  float4 h2 = *(const float4*)(h    + (size_t)wid*DIM + c0);
  float t0=t2.x+h2.x, t1=t2.y+h2.y, t3v=t2.z+h2.z, t4=t2.w+h2.w;
  float mu = half_sum(t0+t1+t3v+t4)*(1.f/128.f);
  float d0=t0-mu, d1=t1-mu, d2=t3v-mu, d3=t4-mu;
  float var = half_sum(d0*d0+d1*d1+d2*d2+d3*d3)*(1.f/128.f);
  float r = rsqrtf(var + 1e-5f);
  float4 gv = *(const float4*)(g+c0);
  float4 bv = *(const float4*)(b+c0);
  float o0=d0*r*gv.x+bv.x, o1=d1*r*gv.y+bv.y, o2=d2*r*gv.z+bv.z, o3=d3*r*gv.w+bv.w;
  float4 o; o.x=o0; o.y=o1; o.z=o2; o.w=o3;
  *(float4*)(h + (size_t)wid*DIM + c0) = o;
  unsigned int u0 = (unsigned int)(unsigned short)f2b(o0) | ((unsigned int)(unsigned short)f2b(o1)<<16);
  unsigned int u1 = (unsigned int)(unsigned short)f2b(o2) | ((unsigned int)(unsigned short)f2b(o3)<<16);
  uint2 ou; ou.x=u0; ou.y=u1;
  *(uint2*)(hb + (size_t)wid*DIM + c0) = ou;
}

// ---------------- mean pool (atomics) + output projection ----------------
__global__ __launch_bounds__(256) void pool_kernel(
  const float* __restrict__ h, const int* __restrict__ batch,
  float* __restrict__ pooled, float* __restrict__ cntB)
{
  int wid  = (blockIdx.x*256 + threadIdx.x) >> 6;
  int lane = threadIdx.x & 63;
  if (wid >= N_NODES) return;
  int bch = batch[wid];
  int ch = lane*2;
  float2 h2 = *(const float2*)(h + (size_t)wid*DIM + ch);
  atomicAdd(&pooled[bch*DIM + ch],     h2.x);
  atomicAdd(&pooled[bch*DIM + ch + 1], h2.y);
  if (lane == 0) atomicAdd(&cntB[bch], 1.0f);
}

__global__ __launch_bounds__(128) void out_kernel(
  const float* __restrict__ pooled, const float* __restrict__ cntB,
  const float* __restrict__ Wout, const float* __restrict__ bout,
  float* __restrict__ out)
{
  int bidx = blockIdx.x;
  int d = threadIdx.x;
  __shared__ float p[DIM];
  float invc = 1.f / fmaxf(cntB[bidx], 1.f);
  p[d] = pooled[bidx*DIM + d] * invc;
  __syncthreads();
  float s = bout[d];
  #pragma unroll 8
  for (int kk=0; kk<DIM; ++kk) s += p[kk]*Wout[kk*DIM + d];
  out[bidx*DIM + d] = s;
}

extern "C" void kernel_launch(void* const* d_in, const int* in_sizes, int n_in,
                              void* d_out, int out_size, void* d_ws, size_t ws_size,
                              hipStream_t stream)
{
  const float* x     = (const float*)d_in[0];
  const float* ea    = (const float*)d_in[1];
  const int*   ei    = (const int*)d_in[2];
  const int*   batch = (const int*)d_in[3];
  const float* Wemb  = (const float*)d_in[4];
  const float* bemb  = (const float*)d_in[5];
  const float* Wout  = (const float*)d_in[6];
  const float* bout  = (const float*)d_in[7];
  const float* Wq    = (const float*)d_in[8];
  const float* bq    = (const float*)d_in[9];
  const float* Wk    = (const float*)d_in[10];
  const float* bk    = (const float*)d_in[11];
  const float* Wv    = (const float*)d_in[12];
  const float* bv    = (const float*)d_in[13];
  const float* We    = (const float*)d_in[14];
  const float* be    = (const float*)d_in[15];
  const float* Wskip = (const float*)d_in[16];
  const float* bskip = (const float*)d_in[17];
  const float* Wbeta = (const float*)d_in[18];
  const float* g1    = (const float*)d_in[19];
  const float* b1    = (const float*)d_in[20];
  const float* g2    = (const float*)d_in[21];
  const float* b2    = (const float*)d_in[22];
  const float* Wf1   = (const float*)d_in[23];
  const float* bf1   = (const float*)d_in[24];
  const float* Wf2   = (const float*)d_in[25];
  const float* bf2   = (const float*)d_in[26];
  float* out = (float*)d_out;

  // ---- workspace layout ----
  float* ws     = (float*)d_ws;
  float* h      = ws;                                  // N*128
  float* ffout  = h + (size_t)N_NODES*DIM;             // N*128
  float* ea_s   = ffout + (size_t)N_NODES*DIM;         // E*12
  float* pooled = ea_s + (size_t)N_EDGES*EDIM;         // B*128
  float* cntB   = pooled + NBATCH*DIM;                 // B
  float* bqkvs  = cntB + NBATCH;                       // L*512
  short* hb     = (short*)(bqkvs + LAYERS*512);        // N*128
  short* region = hb + (size_t)N_NODES*DIM;            // N*512
  short* xb     = region + (size_t)N_NODES*NDFF;       // N*128
  short* wemb_t = xb + (size_t)N_NODES*DIM;            // 128*128
  short* wq_t   = wemb_t + DIM*DIM;                    // L*512*128
  short* wf1_t  = wq_t  + (size_t)LAYERS*NDFF*DIM;
  short* wf2_t  = wf1_t + (size_t)LAYERS*NDFF*DIM;
  int*   cnt       = (int*)(wf2_t + (size_t)LAYERS*NDFF*DIM);
  int*   cnt2      = cnt + N_NODES;
  int*   row_start = cnt2 + N_NODES;                   // N+1
  int*   bsum      = row_start + N_NODES + 1;          // 64
  int*   src_s     = bsum + 64;                        // E

  hipMemsetAsync(cnt,  0, N_NODES*sizeof(int), stream);
  hipMemsetAsync(cnt2, 0, N_NODES*sizeof(int), stream);
  hipMemsetAsync(pooled, 0, (NBATCH*DIM + NBATCH)*sizeof(float), stream);

  // CSR by destination + sorted src/edge_attr
  const int NB_SCAN = (N_NODES + 1023)/1024;           // 49
  count_kernel<<<(N_EDGES+255)/256, 256, 0, stream>>>(ei, cnt);
  scan1<<<NB_SCAN, 1024, 0, stream>>>(cnt, row_start, bsum);
  scan2<<<1, 64, 0, stream>>>(bsum, NB_SCAN);
  scan3<<<(N_NODES+255)/256, 256, 0, stream>>>(row_start, bsum);
  scatter_kernel<<<(N_EDGES+255)/256, 256, 0, stream>>>(ei, ea, cnt2, row_start, src_s, ea_s);

  // pack weights
  pack_weights<<<dim3(768, LAYERS), 256, 0, stream>>>(
      Wq, Wk, Wv, Wskip, bq, bk, bv, bskip, Wf1, Wf2, wq_t, wf1_t, wf2_t, bqkvs);
  pack_emb<<<64, 256, 0, stream>>>(Wemb, wemb_t);
  cast_pad_x<<<(N_NODES*64 + 255)/256, 256, 0, stream>>>(x, xb);

  int gM = (N_NODES + 127)/128;                        // 391
  int attnBlocks = (N_NODES*32 + 255)/256;             // 6250
  int lnBlocks   = (N_NODES*32 + 255)/256;
  int poolBlocks = (N_NODES*64 + 255)/256;

  // h = x @ Wemb + bemb via MFMA (writes fp32 h + bf16 hb)
  mfma_gemm<<<dim3(gM, 1), 256, 0, stream>>>(xb, wemb_t, bemb, h, hb, N_NODES, DIM, DIM, 0);

  for (int l=0; l<LAYERS; ++l){
    // fused Q|K|V|skip projection -> region bf16 [N][512]
    mfma_gemm<<<dim3(gM, 4), 256, 0, stream>>>(
        hb, wq_t + (size_t)l*NDFF*DIM, bqkvs + l*512, nullptr, region,
        N_NODES, DIM, NDFF, 0);

    // attention + beta gate + LN1 -> h, hb
    edge_attn_fused<<<attnBlocks, 256, 0, stream>>>(
        region, ea_s, src_s, We + (size_t)l*EDIM*DIM, be + l*DIM, row_start,
        h, hb, Wbeta + l*3*DIM, g1 + l*DIM, b1 + l*DIM);

    // FF1 (relu) -> region bf16 [N][512]
    mfma_gemm<<<dim3(gM, 4), 256, 0, stream>>>(
        hb, wf1_t + (size_t)l*NDFF*DIM, bf1 + l*NDFF, nullptr, region,
        N_NODES, DIM, NDFF, 1);

    // FF2 -> ffout fp32 [N][128]
    mfma_gemm<<<dim3(gM, 1), 256, 0, stream>>>(
        region, wf2_t + (size_t)l*DIM*NDFF, bf2 + l*DIM, ffout, nullptr,
        N_NODES, NDFF, DIM, 0);

    // residual + LN2 -> h, hb
    add_ln_kernel<<<lnBlocks, 256, 0, stream>>>(ffout, h, hb, g2 + l*DIM, b2 + l*DIM);
  }

  pool_kernel<<<poolBlocks, 256, 0, stream>>>(h, batch, pooled, cntB);
  out_kernel<<<NBATCH, 128, 0, stream>>>(pooled, cntB, Wout, bout, out);
}